// Round 2
// 1468.363 us; speedup vs baseline: 1.0533x; 1.0533x over previous
//
#include <hip/hip_runtime.h>
#include <stdint.h>

#define S_LEN   2048
#define B_SZ    2
#define HIDDEN  2048
#define N_HEADS 16
#define Q_LORA  768
#define KV_LORA 512
#define NOPE    128
#define ROPE    64
#define V_DIM   128
#define QK_HEAD 192
#define KEXT    576
#define EPSV    1e-6f

// packed lower-triangular probs: per z=(b*16+h), 16 row-tiles, tile rt has
// 128 rows of length (rt+1)*128.  triSize = 16384 * (1+2+..+16) = 2,228,224 elems.
#define TRI_Z   2228224

typedef __attribute__((ext_vector_type(8))) short bf16x8;
typedef __attribute__((ext_vector_type(4))) float f32x4;

__device__ __forceinline__ unsigned short f2bf(float f){
  union { float f; unsigned u; } v; v.f = f;
  unsigned u = v.u;
  return (unsigned short)((u + 0x7FFFu + ((u >> 16) & 1u)) >> 16);
}
__device__ __forceinline__ float bf2f(unsigned short h){
  union { unsigned u; float f; } v; v.u = ((unsigned)h) << 16; return v.f;
}

// async global -> LDS, 16 bytes per lane.  LDS dest is wave-uniform base;
// HW adds lane*16.  Global src is per-lane.
__device__ __forceinline__ void gload16(const unsigned short* g, unsigned short* l){
  __builtin_amdgcn_global_load_lds((const __attribute__((address_space(1))) void*)g,
                                   (__attribute__((address_space(3))) void*)l, 16, 0, 0);
}

// ---------------- cast fp32 -> bf16 (vectorized x4) ----------------
__global__ void cast_f32_bf16(const float* __restrict__ in, unsigned short* __restrict__ out, int n4){
  int i = blockIdx.x * blockDim.x + threadIdx.x;
  if (i >= n4) return;
  float4 v = ((const float4*)in)[i];
  ushort4 o;
  o.x = f2bf(v.x); o.y = f2bf(v.y); o.z = f2bf(v.z); o.w = f2bf(v.w);
  ((ushort4*)out)[i] = o;
}

// ---------------- tiled transpose: out[z][c][r] = in[z][r][c] ----------------
// grid (C/64, R/64, Z), block 256.  R,C multiples of 64.
__global__ void transpose_tile(const unsigned short* __restrict__ in, unsigned short* __restrict__ out,
                               int ldin, long inStride, int ldout, long outStride){
  __shared__ unsigned short t[64][65];
  int r0 = blockIdx.y * 64, c0 = blockIdx.x * 64;
  const unsigned short* ib = in + (long)blockIdx.z * inStride;
  unsigned short* ob = out + (long)blockIdx.z * outStride;
  int tid = threadIdx.x;
  #pragma unroll
  for (int i = 0; i < 16; i++) {
    int idx = i * 256 + tid;
    int lr = idx >> 6, lc = idx & 63;
    t[lr][lc] = ib[(long)(r0 + lr) * ldin + c0 + lc];
  }
  __syncthreads();
  #pragma unroll
  for (int i = 0; i < 16; i++) {
    int idx = i * 256 + tid;
    int lr = idx >> 6, lc = idx & 63;
    ob[(long)(c0 + lr) * ldout + r0 + lc] = t[lc][lr];
  }
}

// ---------------- batched MFMA GEMM, A bf16, B bf16 (N,K) row-major ----------------
// C[z] = alpha * A[z] @ B[idxB]^T
//   idxB = (z / bdiv) % bmod
//   C offset = (z/cdiv)*cstride1 + (z%cmod)*cstride2
//   TRI_A: A is packed lower-triangular (see TRI_Z); K-loop bounded by m0+128.
//   SKIP_UPPER: blocks with blockIdx.x > blockIdx.y exit (causal scores).
// Staging: __builtin_amdgcn_global_load_lds width=16, linear [128][32] LDS tiles
// (no padding: gload_lds writes base+lane*16 — m97 structure, ~874 TF class).
// Requires M, K multiples of 128/32 (all call sites satisfy).  N tails (G3 only)
// read garbage rows whose accumulators map to cols >= N and are never stored.
template<bool C_F32, bool TRI_A, bool SKIP_UPPER>
__launch_bounds__(256)
__global__ void gemm_kernel(const unsigned short* __restrict__ A, const unsigned short* __restrict__ B,
                            void* __restrict__ Cv,
                            int M, int N, int K, int lda, int ldb, int ldc,
                            long strideA, long strideB,
                            int bdiv, int bmod,
                            int cdiv, long cstride1, int cmod, long cstride2,
                            float alpha)
{
  if (SKIP_UPPER && blockIdx.x > blockIdx.y) return;

  __shared__ __align__(16) unsigned short As[128*32];
  __shared__ __align__(16) unsigned short Bs[128*32];

  int z  = blockIdx.z;
  int m0 = blockIdx.y * 128;
  int n0 = blockIdx.x * 128;
  int idxB = (z / bdiv) % bmod;
  const unsigned short* Bb = B + (long)idxB * strideB;
  long cOff = (long)(z / cdiv) * cstride1 + (long)(z % cmod) * cstride2;

  int kmax = TRI_A ? (m0 + 128) : K;
  long aBase;
  if (TRI_A) {
    int rt = m0 >> 7;
    aBase = (long)z * strideA + (long)(rt * (rt + 1) / 2) * 16384;
  } else {
    aBase = (long)z * strideA;
  }

  int tid  = threadIdx.x;
  int lane = tid & 63;
  int wid  = tid >> 6;
  int wm   = (wid & 1) * 64;
  int wn   = (wid >> 1) * 64;
  int lrow = lane & 15;
  int kgrp = lane >> 4;

  // staging geometry: wave wid fills LDS bytes [i*4096 + wid*1024, +1024) per
  // half-tile i; lane covers row sR(+i*64), cols sC..sC+7 (shorts).
  int sR = wid * 16 + (lane >> 2);
  int sC = (lane & 3) * 8;
  int aStr = TRI_A ? kmax : lda;
  const unsigned short* aP = A + aBase + (TRI_A ? 0L : (long)m0 * lda) + (long)sR * aStr + sC;
  const unsigned short* bP = Bb + (long)(n0 + sR) * ldb + sC;
  unsigned short* ldsA = &As[wid * 512];   // wave-uniform LDS base
  unsigned short* ldsB = &Bs[wid * 512];

  f32x4 zero = {0.f, 0.f, 0.f, 0.f};
  f32x4 acc[4][4];
  #pragma unroll
  for (int i = 0; i < 4; i++)
    #pragma unroll
    for (int j = 0; j < 4; j++) acc[i][j] = zero;

  for (int k0 = 0; k0 < kmax; k0 += 32) {
    // ---- async stage A/B tiles (4 x global_load_lds_dwordx4 per thread)
    gload16(aP + k0,                      ldsA);
    gload16(aP + (long)64 * aStr + k0,    ldsA + 2048);
    gload16(bP + k0,                      ldsB);
    gload16(bP + (long)64 * ldb + k0,     ldsB + 2048);
    __syncthreads();   // vmcnt(0) drain + barrier: tiles resident

    // ---- fragments + MFMA
    bf16x8 af[4], bfg[4];
    #pragma unroll
    for (int mt = 0; mt < 4; mt++)
      af[mt] = *(const bf16x8*)&As[(wm + mt*16 + lrow)*32 + kgrp*8];
    #pragma unroll
    for (int nt = 0; nt < 4; nt++)
      bfg[nt] = *(const bf16x8*)&Bs[(wn + nt*16 + lrow)*32 + kgrp*8];
    #pragma unroll
    for (int mt = 0; mt < 4; mt++)
      #pragma unroll
      for (int nt = 0; nt < 4; nt++)
        acc[mt][nt] = __builtin_amdgcn_mfma_f32_16x16x32_bf16(af[mt], bfg[nt], acc[mt][nt], 0, 0, 0);
    __syncthreads();   // protect LDS before next iteration's stage
  }

  // ---- epilogue: D[row=(lane>>4)*4+r][col=lane&15]
  #pragma unroll
  for (int mt = 0; mt < 4; mt++) {
    #pragma unroll
    for (int nt = 0; nt < 4; nt++) {
      int col = n0 + wn + nt*16 + lrow;
      if (col >= N) continue;
      int rowb = m0 + wm + mt*16 + kgrp*4;
      #pragma unroll
      for (int r = 0; r < 4; r++) {
        int row = rowb + r;
        if (row >= M) continue;
        float v = acc[mt][nt][r] * alpha;
        if (C_F32) ((float*)Cv)[cOff + (long)row * ldc + col] = v;
        else ((unsigned short*)Cv)[cOff + (long)row * ldc + col] = f2bf(v);
      }
    }
  }
}

// ---------------- RMS norm (q path): 4096 rows x 768 ----------------
__global__ void rmsnorm_q(const float* __restrict__ in, const float* __restrict__ w,
                          unsigned short* __restrict__ out){
  __shared__ float red[4];
  int row = blockIdx.x;
  const float* x = in + (size_t)row * Q_LORA;
  int tid = threadIdx.x;
  float v0 = x[tid], v1 = x[tid + 256], v2 = x[tid + 512];
  float s = v0*v0 + v1*v1 + v2*v2;
  #pragma unroll
  for (int o = 32; o > 0; o >>= 1) s += __shfl_xor(s, o, 64);
  int lane = tid & 63, wid = tid >> 6;
  if (lane == 0) red[wid] = s;
  __syncthreads();
  float tot = red[0] + red[1] + red[2] + red[3];
  float r = rsqrtf(tot * (1.0f / Q_LORA) + EPSV);
  unsigned short* op = out + (size_t)row * Q_LORA;
  op[tid]       = f2bf(v0 * r * w[tid]);
  op[tid + 256] = f2bf(v1 * r * w[tid + 256]);
  op[tid + 512] = f2bf(v2 * r * w[tid + 512]);
}

// ---------------- kv prep: rms-norm 512 + rope 64 -> k_ext (B*S, 576) ----------------
__global__ void kv_prep(const float* __restrict__ kvf, const float* __restrict__ w,
                        const float* __restrict__ cosb, const float* __restrict__ sinb,
                        unsigned short* __restrict__ kext){
  __shared__ float red[4];
  int row = blockIdx.x;   // b*S + s
  const float* x = kvf + (size_t)row * KEXT;
  int tid = threadIdx.x;
  float v0 = x[tid], v1 = x[tid + 256];
  float s = v0*v0 + v1*v1;
  #pragma unroll
  for (int o = 32; o > 0; o >>= 1) s += __shfl_xor(s, o, 64);
  int lane = tid & 63, wid = tid >> 6;
  if (lane == 0) red[wid] = s;
  __syncthreads();
  float tot = red[0] + red[1] + red[2] + red[3];
  float r = rsqrtf(tot * (1.0f / KV_LORA) + EPSV);
  unsigned short* op = kext + (size_t)row * KEXT;
  op[tid]       = f2bf(v0 * r * w[tid]);
  op[tid + 256] = f2bf(v1 * r * w[tid + 256]);
  if (tid < 64) {
    int i = tid;
    float xi = x[512 + i];
    float other = (i < 32) ? -x[512 + i + 32] : x[512 + i - 32];
    float c  = cosb[(size_t)row * 64 + i];
    float sn = sinb[(size_t)row * 64 + i];
    op[512 + i] = f2bf(xi * c + other * sn);
  }
}

// ---------------- q prep: split nope / rope(q_pe); qfull is bf16 ----------------
__global__ void q_prep(const unsigned short* __restrict__ qfull, const float* __restrict__ cosb,
                       const float* __restrict__ sinb, unsigned short* __restrict__ qnope,
                       unsigned short* __restrict__ qext){
  int row = blockIdx.x;          // b*S + s
  int h   = blockIdx.y;
  int b   = row >> 11;
  int s_  = row & 2047;
  const unsigned short* x = qfull + (size_t)row * (N_HEADS * QK_HEAD) + h * QK_HEAD;
  int tid = threadIdx.x;         // 0..191
  long base = ((long)(b * N_HEADS + h) * S_LEN + s_);
  if (tid < 128) {
    qnope[base * NOPE + tid] = x[tid];
  } else {
    int i = tid - 128;           // 0..63
    float xi = bf2f(x[128 + i]);
    float other = (i < 32) ? -bf2f(x[128 + i + 32]) : bf2f(x[128 + i - 32]);
    float c  = cosb[(size_t)row * 64 + i];
    float sn = sinb[(size_t)row * 64 + i];
    qext[base * KEXT + 512 + i] = f2bf(xi * c + other * sn);
  }
}

// ---------------- causal softmax rows (fp32 in-place) + packed bf16 probs ----------------
__global__ void softmax_rows(float* __restrict__ scores, unsigned short* __restrict__ probs){
  __shared__ float red[4];
  int gid = blockIdx.x;          // z*2048 + r
  int z = gid >> 11;
  int r = gid & 2047;
  float* x = scores + (size_t)gid * S_LEN;
  int rt = r >> 7;
  int rowlen = (rt + 1) << 7;
  unsigned short* prow = probs + (long)z * TRI_Z + (long)(rt * (rt + 1) / 2) * 16384
                         + (long)(r - (rt << 7)) * rowlen;
  int tid = threadIdx.x;
  float v[8];
  #pragma unroll
  for (int i = 0; i < 8; i++) {
    int idx = tid + i * 256;
    v[i] = (idx <= r) ? x[idx] : -3.4028234663852886e38f;
  }
  float m = v[0];
  #pragma unroll
  for (int i = 1; i < 8; i++) m = fmaxf(m, v[i]);
  #pragma unroll
  for (int o = 32; o > 0; o >>= 1) m = fmaxf(m, __shfl_xor(m, o, 64));
  int lane = tid & 63, wid = tid >> 6;
  if (lane == 0) red[wid] = m;
  __syncthreads();
  m = fmaxf(fmaxf(red[0], red[1]), fmaxf(red[2], red[3]));
  __syncthreads();
  float s = 0.f;
  #pragma unroll
  for (int i = 0; i < 8; i++) {
    int idx = tid + i * 256;
    v[i] = (idx <= r) ? __expf(v[i] - m) : 0.f;
    s += v[i];
  }
  #pragma unroll
  for (int o = 32; o > 0; o >>= 1) s += __shfl_xor(s, o, 64);
  if (lane == 0) red[wid] = s;
  __syncthreads();
  s = red[0] + red[1] + red[2] + red[3];
  float inv = 1.0f / s;
  #pragma unroll
  for (int i = 0; i < 8; i++) {
    int idx = tid + i * 256;
    float p = v[i] * inv;
    x[idx] = p;
    if (idx < rowlen) prow[idx] = f2bf(p);
  }
}

extern "C" void kernel_launch(void* const* d_in, const int* in_sizes, int n_in,
                              void* d_out, int out_size, void* d_ws, size_t ws_size,
                              hipStream_t stream) {
  const float* hs    = (const float*)d_in[0];
  const float* cosb  = (const float*)d_in[1];
  const float* sinb  = (const float*)d_in[2];
  // d_in[3] = attention_mask — causal, handled analytically in-kernel
  const float* wq_a  = (const float*)d_in[4];
  const float* q_nw  = (const float*)d_in[5];
  const float* wq_b  = (const float*)d_in[6];
  const float* wkv_a = (const float*)d_in[7];
  const float* kv_nw = (const float*)d_in[8];
  const float* wkv_b = (const float*)d_in[9];
  const float* wo    = (const float*)d_in[10];

  float* attn_out = (float*)d_out;
  float* scores   = attn_out + (size_t)B_SZ * S_LEN * HIDDEN;  // attn_weights region

  // ---- workspace layout (bytes). Persistent first, then phase-overlaid arena.
  char* ws = (char*)d_ws;
  const size_t o_wkvb  = 0;                      // 4,194,304  (alive thru G7)
  const size_t o_wo    = 4194304;                // 8,388,608  (alive thru G8)
  const size_t o_kextT = 12582912;               // 4,194,304  (alive thru G6)
  const size_t AR      = 16777216;               // arena base
  // phase A (pre-softmax):
  const size_t o_wqa   = AR + 0;                 // 3,145,728   dead after G1
  const size_t o_wqb   = AR + 3145728;           // 4,718,592   dead after G2
  const size_t o_wkva  = AR + 7864320;           // 2,359,296   dead after G3
  const size_t o_wkvbT = AR + 10223616;          // 2,097,152   dead after G4
  const size_t o_hs    = AR + 12320768;          // 16,777,216  dead after G3
  const size_t o_qa    = AR + 29097984;          // 12,582,912  dead after rmsnorm
  const size_t o_qn    = AR + 41680896;          // 6,291,456   dead after G2
  const size_t o_qfull = AR + 47972352;          // 25,165,824  (bf16) dead after q_prep
  const size_t o_kvf   = AR + 73138176;          // 9,437,184   dead after kv_prep
  const size_t o_kext  = AR + 82575360;          // 4,718,592   dead after G5
  const size_t o_qnope = AR + 87293952;          // 16,777,216  dead after G4
  const size_t o_qext  = AR + 104071168;         // 75,497,472  dead after G5
  // phase B (post-G5; overlays phase A):
  const size_t o_probs = AR + 0;                 // 142,606,336 (packed tri bf16)
  const size_t o_ctx   = AR + 142606336;         // 33,554,432  (per-batch, reused)
  const size_t o_outc  = AR + 176160768;         // 16,777,216
  const size_t total   = AR + 192937984;         // 209,715,200 B = 200 MiB
  if (ws_size < total) return;

  unsigned short* wkvb_bf = (unsigned short*)(ws + o_wkvb);
  unsigned short* wo_bf   = (unsigned short*)(ws + o_wo);
  unsigned short* kextT   = (unsigned short*)(ws + o_kextT);
  unsigned short* wqa_bf  = (unsigned short*)(ws + o_wqa);
  unsigned short* wqb_bf  = (unsigned short*)(ws + o_wqb);
  unsigned short* wkva_bf = (unsigned short*)(ws + o_wkva);
  unsigned short* wkvbT   = (unsigned short*)(ws + o_wkvbT);
  unsigned short* hs_bf   = (unsigned short*)(ws + o_hs);
  float*          qa      = (float*)(ws + o_qa);
  unsigned short* qn      = (unsigned short*)(ws + o_qn);
  unsigned short* qfull   = (unsigned short*)(ws + o_qfull);
  float*          kvf     = (float*)(ws + o_kvf);
  unsigned short* kext    = (unsigned short*)(ws + o_kext);
  unsigned short* qnope   = (unsigned short*)(ws + o_qnope);
  unsigned short* qext    = (unsigned short*)(ws + o_qext);
  unsigned short* probs   = (unsigned short*)(ws + o_probs);
  unsigned short* ctx     = (unsigned short*)(ws + o_ctx);
  unsigned short* outcat  = (unsigned short*)(ws + o_outc);

  auto cast = [&](const float* src, unsigned short* dst, size_t n){
    int n4 = (int)(n / 4);
    cast_f32_bf16<<<dim3((n4 + 255) / 256), dim3(256), 0, stream>>>(src, dst, n4);
  };
  cast(hs,    hs_bf,   (size_t)4096*2048);
  cast(wq_a,  wqa_bf,  (size_t)768*2048);
  cast(wq_b,  wqb_bf,  (size_t)3072*768);
  cast(wkv_a, wkva_bf, (size_t)576*2048);
  cast(wkv_b, wkvb_bf, (size_t)4096*512);
  cast(wo,    wo_bf,   (size_t)2048*2048);

  // wkvbT[h][c][d] = wkv_b[h*256+d][c], d<128  (for G4's B_TRANS path)
  transpose_tile<<<dim3(8,2,16),256,0,stream>>>(wkvb_bf, wkvbT, 512, 131072L, 128, 65536L);

  // G1: qa = hs @ wq_a^T    (4096 x 768, K=2048) fp32 out
  gemm_kernel<true,false,false><<<dim3(6,32,1),256,0,stream>>>(
      hs_bf, wqa_bf, qa, 4096, 768, 2048, 2048, 2048, 768,
      0L, 0L, 1, 1, 1, 0L, 1, 0L, 1.0f);
  rmsnorm_q<<<dim3(4096),dim3(256),0,stream>>>(qa, q_nw, qn);
  // G2: qfull = qn @ wq_b^T (4096 x 3072, K=768) bf16 out
  gemm_kernel<false,false,false><<<dim3(24,32,1),256,0,stream>>>(
      qn, wqb_bf, qfull, 4096, 3072, 768, 768, 768, 3072,
      0L, 0L, 1, 1, 1, 0L, 1, 0L, 1.0f);
  // G3: kvf = hs @ wkv_a^T  (4096 x 576, K=2048) fp32 out
  gemm_kernel<true,false,false><<<dim3(5,32,1),256,0,stream>>>(
      hs_bf, wkva_bf, kvf, 4096, 576, 2048, 2048, 2048, 576,
      0L, 0L, 1, 1, 1, 0L, 1, 0L, 1.0f);
  kv_prep<<<dim3(4096),dim3(256),0,stream>>>(kvf, kv_nw, cosb, sinb, kext);
  // kextT[b][c][s] = kext[b*2048+s][c], c<512  (V^T for G6's B_TRANS path)
  transpose_tile<<<dim3(8,32,2),256,0,stream>>>(kext, kextT, 576, 1179648L, 2048, 1048576L);
  q_prep<<<dim3(4096,16),dim3(192),0,stream>>>(qfull, cosb, sinb, qnope, qext);
  // G4: q_lat = qnope @ wkvbT[h]^T  (per (b,h): 2048x512, K=128) -> qext[:, :512]
  gemm_kernel<false,false,false><<<dim3(4,16,32),256,0,stream>>>(
      qnope, wkvbT, qext, 2048, 512, 128, 128, 128, 576,
      262144L, 65536L, 1, 16, 1, 1179648L, 1, 0L, 1.0f);
  // G5: scores = scale * qext @ kext^T  (per (b,h): 2048x2048, K=576); upper tiles skipped
  gemm_kernel<true,false,true><<<dim3(16,16,32),256,0,stream>>>(
      qext, kext, scores, 2048, 2048, 576, 576, 576, 2048,
      1179648L, 1179648L, 16, 1000000, 1, 4194304L, 1, 0L,
      0.07216878364870322f);
  // softmax: fp32 probs to d_out (full rows incl. zeros), packed bf16 probs to ws
  softmax_rows<<<dim3(65536),dim3(256),0,stream>>>(scores, probs);
  // per-batch: G6 (ctx = probs @ V, triangular-K) then G7 (out_h = ctx @ V_up^T)
  for (int b = 0; b < B_SZ; b++) {
    gemm_kernel<false,true,false><<<dim3(4,16,16),256,0,stream>>>(
        probs + (long)b * 16 * TRI_Z, kextT + (long)b * 1048576, ctx,
        2048, 512, 2048, 0, 2048, 512,
        (long)TRI_Z, 0L, 1, 1, 1, 1048576L, 1, 0L, 1.0f);
    gemm_kernel<false,false,false><<<dim3(1,16,16),256,0,stream>>>(
        ctx, wkvb_bf + 65536, outcat + (long)b * 4194304,
        2048, 128, 512, 512, 512, 2048,
        1048576L, 131072L, 1, 16, 1, 0L, 16, 128L, 1.0f);
  }
  // G8: attn_out = outcat @ wo^T  (4096 x 2048, K=2048) fp32 out
  gemm_kernel<true,false,false><<<dim3(16,32,1),256,0,stream>>>(
      outcat, wo_bf, attn_out, 4096, 2048, 2048, 2048, 2048, 2048,
      0L, 0L, 1, 1, 1, 0L, 1, 0L, 1.0f);
}

// Round 3
// 1373.948 us; speedup vs baseline: 1.1257x; 1.0687x over previous
//
#include <hip/hip_runtime.h>
#include <stdint.h>

#define S_LEN   2048
#define B_SZ    2
#define HIDDEN  2048
#define N_HEADS 16
#define Q_LORA  768
#define KV_LORA 512
#define NOPE    128
#define ROPE    64
#define V_DIM   128
#define QK_HEAD 192
#define KEXT    576
#define EPSV    1e-6f

// packed lower-triangular probs: per z=(b*16+h), 16 row-tiles, tile rt has
// 128 rows of length (rt+1)*128.  triSize = 16384 * (1+2+..+16) = 2,228,224 elems.
#define TRI_Z   2228224

typedef __attribute__((ext_vector_type(8))) short bf16x8;
typedef __attribute__((ext_vector_type(4))) float f32x4;

__device__ __forceinline__ unsigned short f2bf(float f){
  union { float f; unsigned u; } v; v.f = f;
  unsigned u = v.u;
  return (unsigned short)((u + 0x7FFFu + ((u >> 16) & 1u)) >> 16);
}
__device__ __forceinline__ float bf2f(unsigned short h){
  union { unsigned u; float f; } v; v.u = ((unsigned)h) << 16; return v.f;
}

// async global -> LDS, 16 bytes per lane.  LDS dest is wave-uniform base;
// HW adds lane*16.  Global src is per-lane.
__device__ __forceinline__ void gload16(const unsigned short* g, unsigned short* l){
  __builtin_amdgcn_global_load_lds((const __attribute__((address_space(1))) void*)g,
                                   (__attribute__((address_space(3))) void*)l, 16, 0, 0);
}

// ---------------- cast fp32 -> bf16 (vectorized x4) ----------------
__global__ void cast_f32_bf16(const float* __restrict__ in, unsigned short* __restrict__ out, int n4){
  int i = blockIdx.x * blockDim.x + threadIdx.x;
  if (i >= n4) return;
  float4 v = ((const float4*)in)[i];
  ushort4 o;
  o.x = f2bf(v.x); o.y = f2bf(v.y); o.z = f2bf(v.z); o.w = f2bf(v.w);
  ((ushort4*)out)[i] = o;
}

// ---------------- tiled transpose: out[z][c][r] = in[z][r][c] ----------------
// grid (C/64, R/64, Z), block 256.  R,C multiples of 64.
__global__ void transpose_tile(const unsigned short* __restrict__ in, unsigned short* __restrict__ out,
                               int ldin, long inStride, int ldout, long outStride){
  __shared__ unsigned short t[64][65];
  int r0 = blockIdx.y * 64, c0 = blockIdx.x * 64;
  const unsigned short* ib = in + (long)blockIdx.z * inStride;
  unsigned short* ob = out + (long)blockIdx.z * outStride;
  int tid = threadIdx.x;
  #pragma unroll
  for (int i = 0; i < 16; i++) {
    int idx = i * 256 + tid;
    int lr = idx >> 6, lc = idx & 63;
    t[lr][lc] = ib[(long)(r0 + lr) * ldin + c0 + lc];
  }
  __syncthreads();
  #pragma unroll
  for (int i = 0; i < 16; i++) {
    int idx = i * 256 + tid;
    int lr = idx >> 6, lc = idx & 63;
    ob[(long)(c0 + lr) * ldout + r0 + lc] = t[lc][lr];
  }
}

// ---------------- batched MFMA GEMM, A bf16, B bf16 (N,K) row-major ----------------
// C[z] = alpha * A[z] @ B[idxB]^T
//   idxB = (z / bdiv) % bmod
//   C offset = (z/cdiv)*cstride1 + (z%cmod)*cstride2
//   TRI_A: A is packed lower-triangular (see TRI_Z); K-loop bounded by m0+128.
//   SKIP_UPPER: blocks with blockIdx.x > blockIdx.y exit (causal scores).
// Staging: __builtin_amdgcn_global_load_lds width=16, linear [128][32] LDS tiles
// (no padding: gload_lds writes base+lane*16 — m97 structure).
// Requires M, K multiples of 128/32 (all call sites satisfy).  N tails (G3 only)
// read garbage rows whose accumulators map to cols >= N and are never stored.
template<bool C_F32, bool TRI_A, bool SKIP_UPPER>
__launch_bounds__(256)
__global__ void gemm_kernel(const unsigned short* __restrict__ A, const unsigned short* __restrict__ B,
                            void* __restrict__ Cv,
                            int M, int N, int K, int lda, int ldb, int ldc,
                            long strideA, long strideB,
                            int bdiv, int bmod,
                            int cdiv, long cstride1, int cmod, long cstride2,
                            float alpha)
{
  if (SKIP_UPPER && blockIdx.x > blockIdx.y) return;

  __shared__ __align__(16) unsigned short As[128*32];
  __shared__ __align__(16) unsigned short Bs[128*32];

  int z  = blockIdx.z;
  int m0 = blockIdx.y * 128;
  int n0 = blockIdx.x * 128;
  int idxB = (z / bdiv) % bmod;
  const unsigned short* Bb = B + (long)idxB * strideB;
  long cOff = (long)(z / cdiv) * cstride1 + (long)(z % cmod) * cstride2;

  int kmax = TRI_A ? (m0 + 128) : K;
  long aBase;
  if (TRI_A) {
    int rt = m0 >> 7;
    aBase = (long)z * strideA + (long)(rt * (rt + 1) / 2) * 16384;
  } else {
    aBase = (long)z * strideA;
  }

  int tid  = threadIdx.x;
  int lane = tid & 63;
  int wid  = tid >> 6;
  int wm   = (wid & 1) * 64;
  int wn   = (wid >> 1) * 64;
  int lrow = lane & 15;
  int kgrp = lane >> 4;

  // staging geometry: wave wid fills LDS bytes [i*4096 + wid*1024, +1024) per
  // half-tile i; lane covers row sR(+i*64), cols sC..sC+7 (shorts).
  int sR = wid * 16 + (lane >> 2);
  int sC = (lane & 3) * 8;
  int aStr = TRI_A ? kmax : lda;
  const unsigned short* aP = A + aBase + (TRI_A ? 0L : (long)m0 * lda) + (long)sR * aStr + sC;
  const unsigned short* bP = Bb + (long)(n0 + sR) * ldb + sC;
  unsigned short* ldsA = &As[wid * 512];   // wave-uniform LDS base
  unsigned short* ldsB = &Bs[wid * 512];

  f32x4 zero = {0.f, 0.f, 0.f, 0.f};
  f32x4 acc[4][4];
  #pragma unroll
  for (int i = 0; i < 4; i++)
    #pragma unroll
    for (int j = 0; j < 4; j++) acc[i][j] = zero;

  for (int k0 = 0; k0 < kmax; k0 += 32) {
    // ---- async stage A/B tiles (4 x global_load_lds_dwordx4 per thread)
    gload16(aP + k0,                      ldsA);
    gload16(aP + (long)64 * aStr + k0,    ldsA + 2048);
    gload16(bP + k0,                      ldsB);
    gload16(bP + (long)64 * ldb + k0,     ldsB + 2048);
    __syncthreads();   // vmcnt(0) drain + barrier: tiles resident

    // ---- fragments + MFMA
    bf16x8 af[4], bfg[4];
    #pragma unroll
    for (int mt = 0; mt < 4; mt++)
      af[mt] = *(const bf16x8*)&As[(wm + mt*16 + lrow)*32 + kgrp*8];
    #pragma unroll
    for (int nt = 0; nt < 4; nt++)
      bfg[nt] = *(const bf16x8*)&Bs[(wn + nt*16 + lrow)*32 + kgrp*8];
    #pragma unroll
    for (int mt = 0; mt < 4; mt++)
      #pragma unroll
      for (int nt = 0; nt < 4; nt++)
        acc[mt][nt] = __builtin_amdgcn_mfma_f32_16x16x32_bf16(af[mt], bfg[nt], acc[mt][nt], 0, 0, 0);
    __syncthreads();   // protect LDS before next iteration's stage
  }

  // ---- epilogue: D[row=(lane>>4)*4+r][col=lane&15]
  #pragma unroll
  for (int mt = 0; mt < 4; mt++) {
    #pragma unroll
    for (int nt = 0; nt < 4; nt++) {
      int col = n0 + wn + nt*16 + lrow;
      if (col >= N) continue;
      int rowb = m0 + wm + mt*16 + kgrp*4;
      #pragma unroll
      for (int r = 0; r < 4; r++) {
        int row = rowb + r;
        if (row >= M) continue;
        float v = acc[mt][nt][r] * alpha;
        if (C_F32) ((float*)Cv)[cOff + (long)row * ldc + col] = v;
        else ((unsigned short*)Cv)[cOff + (long)row * ldc + col] = f2bf(v);
      }
    }
  }
}

// ---------------- RMS norm (q path): 4096 rows x 768 ----------------
__global__ void rmsnorm_q(const float* __restrict__ in, const float* __restrict__ w,
                          unsigned short* __restrict__ out){
  __shared__ float red[4];
  int row = blockIdx.x;
  const float* x = in + (size_t)row * Q_LORA;
  int tid = threadIdx.x;
  float v0 = x[tid], v1 = x[tid + 256], v2 = x[tid + 512];
  float s = v0*v0 + v1*v1 + v2*v2;
  #pragma unroll
  for (int o = 32; o > 0; o >>= 1) s += __shfl_xor(s, o, 64);
  int lane = tid & 63, wid = tid >> 6;
  if (lane == 0) red[wid] = s;
  __syncthreads();
  float tot = red[0] + red[1] + red[2] + red[3];
  float r = rsqrtf(tot * (1.0f / Q_LORA) + EPSV);
  unsigned short* op = out + (size_t)row * Q_LORA;
  op[tid]       = f2bf(v0 * r * w[tid]);
  op[tid + 256] = f2bf(v1 * r * w[tid + 256]);
  op[tid + 512] = f2bf(v2 * r * w[tid + 512]);
}

// ---------------- kv prep: rms-norm 512 + rope 64 -> k_ext (B*S, 576) ----------------
__global__ void kv_prep(const float* __restrict__ kvf, const float* __restrict__ w,
                        const float* __restrict__ cosb, const float* __restrict__ sinb,
                        unsigned short* __restrict__ kext){
  __shared__ float red[4];
  int row = blockIdx.x;   // b*S + s
  const float* x = kvf + (size_t)row * KEXT;
  int tid = threadIdx.x;
  float v0 = x[tid], v1 = x[tid + 256];
  float s = v0*v0 + v1*v1;
  #pragma unroll
  for (int o = 32; o > 0; o >>= 1) s += __shfl_xor(s, o, 64);
  int lane = tid & 63, wid = tid >> 6;
  if (lane == 0) red[wid] = s;
  __syncthreads();
  float tot = red[0] + red[1] + red[2] + red[3];
  float r = rsqrtf(tot * (1.0f / KV_LORA) + EPSV);
  unsigned short* op = kext + (size_t)row * KEXT;
  op[tid]       = f2bf(v0 * r * w[tid]);
  op[tid + 256] = f2bf(v1 * r * w[tid + 256]);
  if (tid < 64) {
    int i = tid;
    float xi = x[512 + i];
    float other = (i < 32) ? -x[512 + i + 32] : x[512 + i - 32];
    float c  = cosb[(size_t)row * 64 + i];
    float sn = sinb[(size_t)row * 64 + i];
    op[512 + i] = f2bf(xi * c + other * sn);
  }
}

// ---------------- q prep: split nope / rope(q_pe); qfull is bf16 ----------------
__global__ void q_prep(const unsigned short* __restrict__ qfull, const float* __restrict__ cosb,
                       const float* __restrict__ sinb, unsigned short* __restrict__ qnope,
                       unsigned short* __restrict__ qext){
  int row = blockIdx.x;          // b*S + s
  int h   = blockIdx.y;
  int b   = row >> 11;
  int s_  = row & 2047;
  const unsigned short* x = qfull + (size_t)row * (N_HEADS * QK_HEAD) + h * QK_HEAD;
  int tid = threadIdx.x;         // 0..191
  long base = ((long)(b * N_HEADS + h) * S_LEN + s_);
  if (tid < 128) {
    qnope[base * NOPE + tid] = x[tid];
  } else {
    int i = tid - 128;           // 0..63
    float xi = bf2f(x[128 + i]);
    float other = (i < 32) ? -bf2f(x[128 + i + 32]) : bf2f(x[128 + i - 32]);
    float c  = cosb[(size_t)row * 64 + i];
    float sn = sinb[(size_t)row * 64 + i];
    qext[base * KEXT + 512 + i] = f2bf(xi * c + other * sn);
  }
}

// ---------------- causal softmax rows (fp32 in-place) + packed bf16 probs ----------------
__global__ void softmax_rows(float* __restrict__ scores, unsigned short* __restrict__ probs){
  __shared__ float red[4];
  int gid = blockIdx.x;          // z*2048 + r
  int z = gid >> 11;
  int r = gid & 2047;
  float* x = scores + (size_t)gid * S_LEN;
  int rt = r >> 7;
  int rowlen = (rt + 1) << 7;
  unsigned short* prow = probs + (long)z * TRI_Z + (long)(rt * (rt + 1) / 2) * 16384
                         + (long)(r - (rt << 7)) * rowlen;
  int tid = threadIdx.x;
  float v[8];
  #pragma unroll
  for (int i = 0; i < 8; i++) {
    int idx = tid + i * 256;
    v[i] = (idx <= r) ? x[idx] : -3.4028234663852886e38f;
  }
  float m = v[0];
  #pragma unroll
  for (int i = 1; i < 8; i++) m = fmaxf(m, v[i]);
  #pragma unroll
  for (int o = 32; o > 0; o >>= 1) m = fmaxf(m, __shfl_xor(m, o, 64));
  int lane = tid & 63, wid = tid >> 6;
  if (lane == 0) red[wid] = m;
  __syncthreads();
  m = fmaxf(fmaxf(red[0], red[1]), fmaxf(red[2], red[3]));
  __syncthreads();
  float s = 0.f;
  #pragma unroll
  for (int i = 0; i < 8; i++) {
    int idx = tid + i * 256;
    v[i] = (idx <= r) ? __expf(v[i] - m) : 0.f;
    s += v[i];
  }
  #pragma unroll
  for (int o = 32; o > 0; o >>= 1) s += __shfl_xor(s, o, 64);
  if (lane == 0) red[wid] = s;
  __syncthreads();
  s = red[0] + red[1] + red[2] + red[3];
  float inv = 1.0f / s;
  #pragma unroll
  for (int i = 0; i < 8; i++) {
    int idx = tid + i * 256;
    float p = v[i] * inv;
    x[idx] = p;
    if (idx < rowlen) prow[idx] = f2bf(p);
  }
}

extern "C" void kernel_launch(void* const* d_in, const int* in_sizes, int n_in,
                              void* d_out, int out_size, void* d_ws, size_t ws_size,
                              hipStream_t stream) {
  const float* hs    = (const float*)d_in[0];
  const float* cosb  = (const float*)d_in[1];
  const float* sinb  = (const float*)d_in[2];
  // d_in[3] = attention_mask — causal, handled analytically in-kernel
  const float* wq_a  = (const float*)d_in[4];
  const float* q_nw  = (const float*)d_in[5];
  const float* wq_b  = (const float*)d_in[6];
  const float* wkv_a = (const float*)d_in[7];
  const float* kv_nw = (const float*)d_in[8];
  const float* wkv_b = (const float*)d_in[9];
  const float* wo    = (const float*)d_in[10];

  float* attn_out = (float*)d_out;
  float* scores   = attn_out + (size_t)B_SZ * S_LEN * HIDDEN;  // attn_weights region

  // ---- workspace layout (bytes). Persistent first, then phase-overlaid arena.
  char* ws = (char*)d_ws;
  const size_t o_wkvb  = 0;                      // 4,194,304  (alive thru VW gemm)
  const size_t o_wo    = 4194304;                // 8,388,608  (alive thru G8)
  const size_t AR      = 16777216;               // arena base
  // phase A (pre-softmax):
  const size_t o_wqa   = AR + 0;                 // 3,145,728   dead after G1
  const size_t o_wqb   = AR + 3145728;           // 4,718,592   dead after G2
  const size_t o_wkva  = AR + 7864320;           // 2,359,296   dead after G3
  const size_t o_wkvbT = AR + 10223616;          // 2,097,152   dead after G4
  const size_t o_hs    = AR + 12320768;          // 16,777,216  dead after G3
  const size_t o_qa    = AR + 29097984;          // 12,582,912  dead after rmsnorm
  const size_t o_qn    = AR + 41680896;          // 6,291,456   dead after G2
  const size_t o_qfull = AR + 47972352;          // 25,165,824  (bf16) dead after q_prep
  const size_t o_kvf   = AR + 73138176;          // 9,437,184   dead after kv_prep
  const size_t o_kext  = AR + 82575360;          // 4,718,592   dead after VW gemm
  const size_t o_qnope = AR + 87293952;          // 16,777,216  dead after G4
  const size_t o_qext  = AR + 104071168;         // 75,497,472  dead after G5
  // phase B (post-G5; overlays phase A):
  const size_t o_probs = AR + 0;                 // 142,606,336 (packed tri bf16)
  const size_t o_vwT   = AR + 142606336;         // 16,777,216  VW^T (32 x 128 x 2048 bf16)
  const size_t o_outc  = AR + 176160768;         // 16,777,216
  const size_t total   = AR + 192937984;         // 209,715,200 B = 200 MiB
  if (ws_size < total) return;

  unsigned short* wkvb_bf = (unsigned short*)(ws + o_wkvb);
  unsigned short* wo_bf   = (unsigned short*)(ws + o_wo);
  unsigned short* wqa_bf  = (unsigned short*)(ws + o_wqa);
  unsigned short* wqb_bf  = (unsigned short*)(ws + o_wqb);
  unsigned short* wkva_bf = (unsigned short*)(ws + o_wkva);
  unsigned short* wkvbT   = (unsigned short*)(ws + o_wkvbT);
  unsigned short* hs_bf   = (unsigned short*)(ws + o_hs);
  float*          qa      = (float*)(ws + o_qa);
  unsigned short* qn      = (unsigned short*)(ws + o_qn);
  unsigned short* qfull   = (unsigned short*)(ws + o_qfull);
  float*          kvf     = (float*)(ws + o_kvf);
  unsigned short* kext    = (unsigned short*)(ws + o_kext);
  unsigned short* qnope   = (unsigned short*)(ws + o_qnope);
  unsigned short* qext    = (unsigned short*)(ws + o_qext);
  unsigned short* probs   = (unsigned short*)(ws + o_probs);
  unsigned short* vwT     = (unsigned short*)(ws + o_vwT);
  unsigned short* outcat  = (unsigned short*)(ws + o_outc);

  auto cast = [&](const float* src, unsigned short* dst, size_t n){
    int n4 = (int)(n / 4);
    cast_f32_bf16<<<dim3((n4 + 255) / 256), dim3(256), 0, stream>>>(src, dst, n4);
  };
  cast(hs,    hs_bf,   (size_t)4096*2048);
  cast(wq_a,  wqa_bf,  (size_t)768*2048);
  cast(wq_b,  wqb_bf,  (size_t)3072*768);
  cast(wkv_a, wkva_bf, (size_t)576*2048);
  cast(wkv_b, wkvb_bf, (size_t)4096*512);
  cast(wo,    wo_bf,   (size_t)2048*2048);

  // wkvbT[h][c][d] = wkv_b[h*256+d][c], d<128  (for G4's B_TRANS path)
  transpose_tile<<<dim3(8,2,16),256,0,stream>>>(wkvb_bf, wkvbT, 512, 131072L, 128, 65536L);

  // G1: qa = hs @ wq_a^T    (4096 x 768, K=2048) fp32 out
  gemm_kernel<true,false,false><<<dim3(6,32,1),256,0,stream>>>(
      hs_bf, wqa_bf, qa, 4096, 768, 2048, 2048, 2048, 768,
      0L, 0L, 1, 1, 1, 0L, 1, 0L, 1.0f);
  rmsnorm_q<<<dim3(4096),dim3(256),0,stream>>>(qa, q_nw, qn);
  // G2: qfull = qn @ wq_b^T (4096 x 3072, K=768) bf16 out
  gemm_kernel<false,false,false><<<dim3(24,32,1),256,0,stream>>>(
      qn, wqb_bf, qfull, 4096, 3072, 768, 768, 768, 3072,
      0L, 0L, 1, 1, 1, 0L, 1, 0L, 1.0f);
  // G3: kvf = hs @ wkv_a^T  (4096 x 576, K=2048) fp32 out
  gemm_kernel<true,false,false><<<dim3(5,32,1),256,0,stream>>>(
      hs_bf, wkva_bf, kvf, 4096, 576, 2048, 2048, 2048, 576,
      0L, 0L, 1, 1, 1, 0L, 1, 0L, 1.0f);
  kv_prep<<<dim3(4096),dim3(256),0,stream>>>(kvf, kv_nw, cosb, sinb, kext);
  q_prep<<<dim3(4096,16),dim3(192),0,stream>>>(qfull, cosb, sinb, qnope, qext);
  // G4: q_lat = qnope @ wkvbT[h]^T  (per (b,h): 2048x512, K=128) -> qext[:, :512]
  gemm_kernel<false,false,false><<<dim3(4,16,32),256,0,stream>>>(
      qnope, wkvbT, qext, 2048, 512, 128, 128, 128, 576,
      262144L, 65536L, 1, 16, 1, 1179648L, 1, 0L, 1.0f);
  // G5: scores = scale * qext @ kext^T  (per (b,h): 2048x2048, K=576); upper tiles skipped
  gemm_kernel<true,false,true><<<dim3(16,16,32),256,0,stream>>>(
      qext, kext, scores, 2048, 2048, 576, 576, 576, 2048,
      1179648L, 1179648L, 16, 1000000, 1, 4194304L, 1, 0L,
      0.07216878364870322f);
  // GVW: vwT[b*16+h][d][s] = sum_c W_v[h][d][c] * kv[b][s][c]
  //   A = wkv_b V-part (rows h*256+128..+255), M=128, K=512, per-h stride 131072
  //   B = kext[b] (2048 x 576, first 512 cols), N=2048
  //   (runs after G5: vwT region overlays dead qext)
  for (int b = 0; b < B_SZ; b++) {
    gemm_kernel<false,false,false><<<dim3(16,1,16),256,0,stream>>>(
        wkvb_bf + 65536, kext + (long)b * 2048 * KEXT, vwT + (long)b * 4194304,
        128, 2048, 512, 512, KEXT, 2048,
        131072L, 0L, 1, 1, 1, 262144L, 1, 0L, 1.0f);
  }
  // softmax: fp32 probs to d_out (full rows incl. zeros), packed bf16 probs to ws
  softmax_rows<<<dim3(65536),dim3(256),0,stream>>>(scores, probs);
  // GPV: out_h = probs @ vwT^T  (per (b,h): 2048 x 128, triangular-K) -> outcat
  for (int b = 0; b < B_SZ; b++) {
    gemm_kernel<false,true,false><<<dim3(1,16,16),256,0,stream>>>(
        probs + (long)b * 16 * TRI_Z, vwT + (long)b * 4194304, outcat + (long)b * 4194304,
        2048, 128, 2048, 0, 2048, 2048,
        (long)TRI_Z, 262144L, 1, 16, 1, 0L, 16, 128L, 1.0f);
  }
  // G8: attn_out = outcat @ wo^T  (4096 x 2048, K=2048) fp32 out
  gemm_kernel<true,false,false><<<dim3(16,32,1),256,0,stream>>>(
      outcat, wo_bf, attn_out, 4096, 2048, 2048, 2048, 2048, 2048,
      0L, 0L, 1, 1, 1, 0L, 1, 0L, 1.0f);
}

// Round 7
// 1211.507 us; speedup vs baseline: 1.2766x; 1.1341x over previous
//
#include <hip/hip_runtime.h>
#include <stdint.h>

#define S_LEN   2048
#define B_SZ    2
#define HIDDEN  2048
#define N_HEADS 16
#define Q_LORA  768
#define KV_LORA 512
#define NOPE    128
#define ROPE    64
#define V_DIM   128
#define QK_HEAD 192
#define KEXT    576
#define EPSV    1e-6f
#define QKC_LD  1344   /* fused G1+G3 output row stride (768 + 576) */

// packed lower-triangular probs: per z=(b*16+h), 16 row-tiles, tile rt has
// 128 rows of length (rt+1)*128.  triSize = 16384 * (1+2+..+16) = 2,228,224 elems.
#define TRI_Z   2228224

typedef __attribute__((ext_vector_type(8))) short bf16x8;
typedef __attribute__((ext_vector_type(4))) float f32x4;

__device__ __forceinline__ unsigned short f2bf(float f){
  union { float f; unsigned u; } v; v.f = f;
  unsigned u = v.u;
  return (unsigned short)((u + 0x7FFFu + ((u >> 16) & 1u)) >> 16);
}
__device__ __forceinline__ float bf2f(unsigned short h){
  union { unsigned u; float f; } v; v.u = ((unsigned)h) << 16; return v.f;
}

// async global -> LDS, 16 bytes per lane.  LDS dest is wave-uniform base;
// HW adds lane*16.  Global src is per-lane.
__device__ __forceinline__ void gload16(const unsigned short* g, unsigned short* l){
  __builtin_amdgcn_global_load_lds((const __attribute__((address_space(1))) void*)g,
                                   (__attribute__((address_space(3))) void*)l, 16, 0, 0);
}

// ---------------- single fused cast fp32 -> bf16 for all 6 inputs ----------------
// segment prefix sums in float4 units (compile-time constants)
#define C_HS   2097152            /* 4096*2048/4 */
#define C_WQA  (C_HS   + 393216)  /* 768*2048/4  */
#define C_WQB  (C_WQA  + 589824)  /* 3072*768/4  */
#define C_WKVA (C_WQB  + 294912)  /* 576*2048/4  */
#define C_WKVB (C_WKVA + 524288)  /* 4096*512/4  */
#define C_WO   (C_WKVB + 1048576) /* 2048*2048/4 */
__global__ void cast_all(const float* __restrict__ hs, const float* __restrict__ wqa,
                         const float* __restrict__ wqb, const float* __restrict__ wkva,
                         const float* __restrict__ wkvb, const float* __restrict__ wo,
                         unsigned short* __restrict__ d_hs, unsigned short* __restrict__ d_wqa,
                         unsigned short* __restrict__ d_wqb, unsigned short* __restrict__ d_wkva,
                         unsigned short* __restrict__ d_wkvb, unsigned short* __restrict__ d_wo){
  int i = blockIdx.x * blockDim.x + threadIdx.x;
  const float* s; unsigned short* d; int j;
  if      (i < C_HS)   { s = hs;   d = d_hs;   j = i; }
  else if (i < C_WQA)  { s = wqa;  d = d_wqa;  j = i - C_HS; }
  else if (i < C_WQB)  { s = wqb;  d = d_wqb;  j = i - C_WQA; }
  else if (i < C_WKVA) { s = wkva; d = d_wkva; j = i - C_WQB; }
  else if (i < C_WKVB) { s = wkvb; d = d_wkvb; j = i - C_WKVA; }
  else if (i < C_WO)   { s = wo;   d = d_wo;   j = i - C_WKVB; }
  else return;
  float4 v = ((const float4*)s)[j];
  ushort4 o;
  o.x = f2bf(v.x); o.y = f2bf(v.y); o.z = f2bf(v.z); o.w = f2bf(v.w);
  ((ushort4*)d)[j] = o;
}

// ---------------- tiled transpose: out[z][c][r] = in[z][r][c] ----------------
// grid (C/64, R/64, Z), block 256.  R,C multiples of 64.
__global__ void transpose_tile(const unsigned short* __restrict__ in, unsigned short* __restrict__ out,
                               int ldin, long inStride, int ldout, long outStride){
  __shared__ unsigned short t[64][65];
  int r0 = blockIdx.y * 64, c0 = blockIdx.x * 64;
  const unsigned short* ib = in + (long)blockIdx.z * inStride;
  unsigned short* ob = out + (long)blockIdx.z * outStride;
  int tid = threadIdx.x;
  #pragma unroll
  for (int i = 0; i < 16; i++) {
    int idx = i * 256 + tid;
    int lr = idx >> 6, lc = idx & 63;
    t[lr][lc] = ib[(long)(r0 + lr) * ldin + c0 + lc];
  }
  __syncthreads();
  #pragma unroll
  for (int i = 0; i < 16; i++) {
    int idx = i * 256 + tid;
    int lr = idx >> 6, lc = idx & 63;
    ob[(long)(c0 + lr) * ldout + r0 + lc] = t[lc][lr];
  }
}

// ---------------- batched MFMA GEMM, A bf16, B bf16 (N,K) row-major ----------------
// C[z] = alpha * A[idxA] @ B[idxB]^T
//   idxA = (z / adiv) % amod,  idxB = (z / bdiv) % bmod
//   C offset = (z/cdiv)*cstride1 + (z%cmod)*cstride2
//   TRI_A: A is packed lower-triangular (see TRI_Z); K-loop bounded by m0+128.
//   SKIP_UPPER: blocks with blockIdx.x > blockIdx.y exit (causal scores).
// Staging: __builtin_amdgcn_global_load_lds width=16 into two 16KB [128][32]
// sub-tile buffers per operand; 2 K-steps (64 K) per barrier pair — halves the
// sync-round count vs 1-step while keeping the 8-way (not 16-way) ds_read
// conflict of the [128][32] layout and 32 KB LDS (occupancy VGPR-capped, not
// LDS-capped).  Requires K % 64 == 0 and M % 128 == 0 (all call sites satisfy).
// N tails read garbage rows whose accumulator columns >= N are never stored.
template<bool C_F32, bool TRI_A, bool SKIP_UPPER>
__launch_bounds__(256)
__global__ void gemm_kernel(const unsigned short* __restrict__ A, const unsigned short* __restrict__ B,
                            void* __restrict__ Cv,
                            int M, int N, int K, int lda, int ldb, int ldc,
                            long strideA, long strideB,
                            int adiv, int amod,
                            int bdiv, int bmod,
                            int cdiv, long cstride1, int cmod, long cstride2,
                            float alpha)
{
  if (SKIP_UPPER && blockIdx.x > blockIdx.y) return;

  __shared__ __align__(16) unsigned short As[2*128*32];
  __shared__ __align__(16) unsigned short Bs[2*128*32];

  int z  = blockIdx.z;
  int m0 = blockIdx.y * 128;
  int n0 = blockIdx.x * 128;
  int idxA = (z / adiv) % amod;
  int idxB = (z / bdiv) % bmod;
  const unsigned short* Bb = B + (long)idxB * strideB;
  long cOff = (long)(z / cdiv) * cstride1 + (long)(z % cmod) * cstride2;

  int kmax = TRI_A ? (m0 + 128) : K;
  long aBase;
  if (TRI_A) {
    int rt = m0 >> 7;
    aBase = (long)idxA * strideA + (long)(rt * (rt + 1) / 2) * 16384;
  } else {
    aBase = (long)idxA * strideA;
  }

  int tid  = threadIdx.x;
  int lane = tid & 63;
  int wid  = tid >> 6;
  int wm   = (wid & 1) * 64;
  int wn   = (wid >> 1) * 64;
  int lrow = lane & 15;
  int kgrp = lane >> 4;

  // staging geometry (per 32-wide sub-tile): wave wid fills LDS shorts
  // [subtile*4096 + wid*512 + i*2048, +512) ; lane covers row sR(+i*64),
  // cols sC..sC+7 (shorts) of the sub-tile.
  int sR = wid * 16 + (lane >> 2);
  int sC = (lane & 3) * 8;
  int aStr = TRI_A ? kmax : lda;
  const unsigned short* aP = A + aBase + (TRI_A ? 0L : (long)m0 * lda) + (long)sR * aStr + sC;
  const unsigned short* bP = Bb + (long)(n0 + sR) * ldb + sC;
  unsigned short* ldsA = &As[wid * 512];   // wave-uniform LDS base (sub-tile 0)
  unsigned short* ldsB = &Bs[wid * 512];

  f32x4 zero = {0.f, 0.f, 0.f, 0.f};
  f32x4 acc[4][4];
  #pragma unroll
  for (int i = 0; i < 4; i++)
    #pragma unroll
    for (int j = 0; j < 4; j++) acc[i][j] = zero;

  for (int k0 = 0; k0 < kmax; k0 += 64) {
    // ---- async stage 2 K-sub-tiles of A and B (8 x global_load_lds_dwordx4)
    gload16(aP + k0,                             ldsA);
    gload16(aP + (long)64 * aStr + k0,           ldsA + 2048);
    gload16(aP + (k0 + 32),                      ldsA + 4096);
    gload16(aP + (long)64 * aStr + (k0 + 32),    ldsA + 4096 + 2048);
    gload16(bP + k0,                             ldsB);
    gload16(bP + (long)64 * ldb + k0,            ldsB + 2048);
    gload16(bP + (k0 + 32),                      ldsB + 4096);
    gload16(bP + (long)64 * ldb + (k0 + 32),     ldsB + 4096 + 2048);
    __syncthreads();   // vmcnt(0) drain + barrier: both sub-tiles resident

    // ---- fragments + MFMA, 2 sub-steps (same FP accumulation order as K-step 32)
    #pragma unroll
    for (int kk = 0; kk < 2; kk++) {
      bf16x8 af[4], bfg[4];
      #pragma unroll
      for (int mt = 0; mt < 4; mt++)
        af[mt] = *(const bf16x8*)&As[kk*4096 + (wm + mt*16 + lrow)*32 + kgrp*8];
      #pragma unroll
      for (int nt = 0; nt < 4; nt++)
        bfg[nt] = *(const bf16x8*)&Bs[kk*4096 + (wn + nt*16 + lrow)*32 + kgrp*8];
      #pragma unroll
      for (int mt = 0; mt < 4; mt++)
        #pragma unroll
        for (int nt = 0; nt < 4; nt++)
          acc[mt][nt] = __builtin_amdgcn_mfma_f32_16x16x32_bf16(af[mt], bfg[nt], acc[mt][nt], 0, 0, 0);
    }
    __syncthreads();   // protect LDS before next round's stage
  }

  // ---- epilogue: D[row=(lane>>4)*4+r][col=lane&15]
  #pragma unroll
  for (int mt = 0; mt < 4; mt++) {
    #pragma unroll
    for (int nt = 0; nt < 4; nt++) {
      int col = n0 + wn + nt*16 + lrow;
      if (col >= N) continue;
      int rowb = m0 + wm + mt*16 + kgrp*4;
      #pragma unroll
      for (int r = 0; r < 4; r++) {
        int row = rowb + r;
        if (row >= M) continue;
        float v = acc[mt][nt][r] * alpha;
        if (C_F32) ((float*)Cv)[cOff + (long)row * ldc + col] = v;
        else ((unsigned short*)Cv)[cOff + (long)row * ldc + col] = f2bf(v);
      }
    }
  }
}

// ---------------- RMS norm (q path): 4096 rows x 768, src rows ld=1344 ----------------
__global__ void rmsnorm_q(const float* __restrict__ in, const float* __restrict__ w,
                          unsigned short* __restrict__ out){
  __shared__ float red[4];
  int row = blockIdx.x;
  const float* x = in + (size_t)row * QKC_LD;
  int tid = threadIdx.x;
  float v0 = x[tid], v1 = x[tid + 256], v2 = x[tid + 512];
  float s = v0*v0 + v1*v1 + v2*v2;
  #pragma unroll
  for (int o = 32; o > 0; o >>= 1) s += __shfl_xor(s, o, 64);
  int lane = tid & 63, wid = tid >> 6;
  if (lane == 0) red[wid] = s;
  __syncthreads();
  float tot = red[0] + red[1] + red[2] + red[3];
  float r = rsqrtf(tot * (1.0f / Q_LORA) + EPSV);
  unsigned short* op = out + (size_t)row * Q_LORA;
  op[tid]       = f2bf(v0 * r * w[tid]);
  op[tid + 256] = f2bf(v1 * r * w[tid + 256]);
  op[tid + 512] = f2bf(v2 * r * w[tid + 512]);
}

// ---------------- kv prep: rms-norm 512 + rope 64 -> k_ext (B*S, 576) ----------------
// src = fused qkc buffer, kv part at col 768, row stride 1344
__global__ void kv_prep(const float* __restrict__ qkc, const float* __restrict__ w,
                        const float* __restrict__ cosb, const float* __restrict__ sinb,
                        unsigned short* __restrict__ kext){
  __shared__ float red[4];
  int row = blockIdx.x;   // b*S + s
  const float* x = qkc + (size_t)row * QKC_LD + Q_LORA;
  int tid = threadIdx.x;
  float v0 = x[tid], v1 = x[tid + 256];
  float s = v0*v0 + v1*v1;
  #pragma unroll
  for (int o = 32; o > 0; o >>= 1) s += __shfl_xor(s, o, 64);
  int lane = tid & 63, wid = tid >> 6;
  if (lane == 0) red[wid] = s;
  __syncthreads();
  float tot = red[0] + red[1] + red[2] + red[3];
  float r = rsqrtf(tot * (1.0f / KV_LORA) + EPSV);
  unsigned short* op = kext + (size_t)row * KEXT;
  op[tid]       = f2bf(v0 * r * w[tid]);
  op[tid + 256] = f2bf(v1 * r * w[tid + 256]);
  if (tid < 64) {
    int i = tid;
    float xi = x[512 + i];
    float other = (i < 32) ? -x[512 + i + 32] : x[512 + i - 32];
    float c  = cosb[(size_t)row * 64 + i];
    float sn = sinb[(size_t)row * 64 + i];
    op[512 + i] = f2bf(xi * c + other * sn);
  }
}

// ---------------- q prep: split nope / rope(q_pe); qfull is bf16 ----------------
__global__ void q_prep(const unsigned short* __restrict__ qfull, const float* __restrict__ cosb,
                       const float* __restrict__ sinb, unsigned short* __restrict__ qnope,
                       unsigned short* __restrict__ qext){
  int row = blockIdx.x;          // b*S + s
  int h   = blockIdx.y;
  int b   = row >> 11;
  int s_  = row & 2047;
  const unsigned short* x = qfull + (size_t)row * (N_HEADS * QK_HEAD) + h * QK_HEAD;
  int tid = threadIdx.x;         // 0..191
  long base = ((long)(b * N_HEADS + h) * S_LEN + s_);
  if (tid < 128) {
    qnope[base * NOPE + tid] = x[tid];
  } else {
    int i = tid - 128;           // 0..63
    float xi = bf2f(x[128 + i]);
    float other = (i < 32) ? -bf2f(x[128 + i + 32]) : bf2f(x[128 + i - 32]);
    float c  = cosb[(size_t)row * 64 + i];
    float sn = sinb[(size_t)row * 64 + i];
    qext[base * KEXT + 512 + i] = f2bf(xi * c + other * sn);
  }
}

// ---------------- causal softmax rows (fp32 in-place) + packed bf16 probs ----------------
__global__ void softmax_rows(float* __restrict__ scores, unsigned short* __restrict__ probs){
  __shared__ float red[4];
  int gid = blockIdx.x;          // z*2048 + r
  int z = gid >> 11;
  int r = gid & 2047;
  float* x = scores + (size_t)gid * S_LEN;
  int rt = r >> 7;
  int rowlen = (rt + 1) << 7;
  unsigned short* prow = probs + (long)z * TRI_Z + (long)(rt * (rt + 1) / 2) * 16384
                         + (long)(r - (rt << 7)) * rowlen;
  int tid = threadIdx.x;
  float v[8];
  #pragma unroll
  for (int i = 0; i < 8; i++) {
    int idx = tid + i * 256;
    v[i] = (idx <= r) ? x[idx] : -3.4028234663852886e38f;
  }
  float m = v[0];
  #pragma unroll
  for (int i = 1; i < 8; i++) m = fmaxf(m, v[i]);
  #pragma unroll
  for (int o = 32; o > 0; o >>= 1) m = fmaxf(m, __shfl_xor(m, o, 64));
  int lane = tid & 63, wid = tid >> 6;
  if (lane == 0) red[wid] = m;
  __syncthreads();
  m = fmaxf(fmaxf(red[0], red[1]), fmaxf(red[2], red[3]));
  __syncthreads();
  float s = 0.f;
  #pragma unroll
  for (int i = 0; i < 8; i++) {
    int idx = tid + i * 256;
    v[i] = (idx <= r) ? __expf(v[i] - m) : 0.f;
    s += v[i];
  }
  #pragma unroll
  for (int o = 32; o > 0; o >>= 1) s += __shfl_xor(s, o, 64);
  if (lane == 0) red[wid] = s;
  __syncthreads();
  s = red[0] + red[1] + red[2] + red[3];
  float inv = 1.0f / s;
  #pragma unroll
  for (int i = 0; i < 8; i++) {
    int idx = tid + i * 256;
    float p = v[i] * inv;
    x[idx] = p;
    if (idx < rowlen) prow[idx] = f2bf(p);
  }
}

extern "C" void kernel_launch(void* const* d_in, const int* in_sizes, int n_in,
                              void* d_out, int out_size, void* d_ws, size_t ws_size,
                              hipStream_t stream) {
  const float* hs    = (const float*)d_in[0];
  const float* cosb  = (const float*)d_in[1];
  const float* sinb  = (const float*)d_in[2];
  // d_in[3] = attention_mask — causal, handled analytically in-kernel
  const float* wq_a  = (const float*)d_in[4];
  const float* q_nw  = (const float*)d_in[5];
  const float* wq_b  = (const float*)d_in[6];
  const float* wkv_a = (const float*)d_in[7];
  const float* kv_nw = (const float*)d_in[8];
  const float* wkv_b = (const float*)d_in[9];
  const float* wo    = (const float*)d_in[10];

  float* attn_out = (float*)d_out;
  float* scores   = attn_out + (size_t)B_SZ * S_LEN * HIDDEN;  // attn_weights region

  // ---- workspace layout (bytes). Persistent first, then phase-overlaid arena.
  char* ws = (char*)d_ws;
  const size_t o_wkvb  = 0;                      // 4,194,304  (alive thru GVW)
  const size_t o_wo    = 4194304;                // 8,388,608  (alive thru G8)
  const size_t AR      = 16777216;               // arena base
  // phase A (pre-softmax).  wqa and wkva are ADJACENT (fused G1+G3 B operand).
  const size_t o_wqa   = AR + 0;                 // 3,145,728   dead after G1G3
  const size_t o_wkva  = AR + 3145728;           // 2,359,296   dead after G1G3
  const size_t o_wqb   = AR + 5505024;           // 4,718,592   dead after G2
  const size_t o_wkvbT = AR + 10223616;          // 2,097,152   dead after G4
  const size_t o_hs    = AR + 12320768;          // 16,777,216  dead after G1G3
  const size_t o_qkc   = AR + 29097984;          // 22,020,096  fp32 4096x1344, dead after preps
  const size_t o_qn    = AR + 51118080;          // 6,291,456   dead after G2
  const size_t o_qfull = AR + 57409536;          // 25,165,824  (bf16) dead after q_prep
  const size_t o_kext  = AR + 82575360;          // 4,718,592   dead after GVW
  const size_t o_qnope = AR + 87293952;          // 16,777,216  dead after G4
  const size_t o_qext  = AR + 104071168;         // 75,497,472  dead after G5
  // phase B (post-G5; overlays phase A):
  const size_t o_probs = AR + 0;                 // 142,606,336 (packed tri bf16, after GVW)
  const size_t o_vwT   = AR + 142606336;         // 16,777,216  VW^T (32 x 128 x 2048 bf16)
  const size_t o_outc  = AR + 176160768;         // 16,777,216
  const size_t total   = AR + 192937984;         // 209,715,200 B = 200 MiB
  if (ws_size < total) return;

  unsigned short* wkvb_bf = (unsigned short*)(ws + o_wkvb);
  unsigned short* wo_bf   = (unsigned short*)(ws + o_wo);
  unsigned short* wqa_bf  = (unsigned short*)(ws + o_wqa);
  unsigned short* wkva_bf = (unsigned short*)(ws + o_wkva);
  unsigned short* wqb_bf  = (unsigned short*)(ws + o_wqb);
  unsigned short* wkvbT   = (unsigned short*)(ws + o_wkvbT);
  unsigned short* hs_bf   = (unsigned short*)(ws + o_hs);
  float*          qkc     = (float*)(ws + o_qkc);
  unsigned short* qn      = (unsigned short*)(ws + o_qn);
  unsigned short* qfull   = (unsigned short*)(ws + o_qfull);
  unsigned short* kext    = (unsigned short*)(ws + o_kext);
  unsigned short* qnope   = (unsigned short*)(ws + o_qnope);
  unsigned short* qext    = (unsigned short*)(ws + o_qext);
  unsigned short* probs   = (unsigned short*)(ws + o_probs);
  unsigned short* vwT     = (unsigned short*)(ws + o_vwT);
  unsigned short* outcat  = (unsigned short*)(ws + o_outc);

  // single fused cast of all fp32 inputs to bf16
  cast_all<<<dim3((C_WO + 255) / 256), dim3(256), 0, stream>>>(
      hs, wq_a, wq_b, wkv_a, wkv_b, wo,
      hs_bf, wqa_bf, wqb_bf, wkva_bf, wkvb_bf, wo_bf);

  // wkvbT[h][c][d] = wkv_b[h*256+d][c], d<128  (for G4's B_TRANS path)
  transpose_tile<<<dim3(8,2,16),256,0,stream>>>(wkvb_bf, wkvbT, 512, 131072L, 128, 65536L);

  // G1G3 fused: qkc = hs @ [wq_a | wkv_a]^T  (4096 x 1344, K=2048) fp32 out
  gemm_kernel<true,false,false><<<dim3(11,32,1),256,0,stream>>>(
      hs_bf, wqa_bf, qkc, 4096, 1344, 2048, 2048, 2048, QKC_LD,
      0L, 0L, 1, 1, 1, 1, 1, 0L, 1, 0L, 1.0f);
  rmsnorm_q<<<dim3(4096),dim3(256),0,stream>>>(qkc, q_nw, qn);
  kv_prep<<<dim3(4096),dim3(256),0,stream>>>(qkc, kv_nw, cosb, sinb, kext);
  // G2: qfull = qn @ wq_b^T (4096 x 3072, K=768) bf16 out
  gemm_kernel<false,false,false><<<dim3(24,32,1),256,0,stream>>>(
      qn, wqb_bf, qfull, 4096, 3072, 768, 768, 768, 3072,
      0L, 0L, 1, 1, 1, 1, 1, 0L, 1, 0L, 1.0f);
  q_prep<<<dim3(4096,16),dim3(192),0,stream>>>(qfull, cosb, sinb, qnope, qext);
  // G4: q_lat = qnope @ wkvbT[h]^T  (per z=(b,h): 2048x512, K=128) -> qext[:, :512]
  gemm_kernel<false,false,false><<<dim3(4,16,32),256,0,stream>>>(
      qnope, wkvbT, qext, 2048, 512, 128, 128, 128, 576,
      262144L, 65536L, 1, 1000000, 1, 16, 1, 1179648L, 1, 0L, 1.0f);
  // G5: scores = scale * qext @ kext^T  (per z: 2048x2048, K=576); upper tiles skipped
  gemm_kernel<true,false,true><<<dim3(16,16,32),256,0,stream>>>(
      qext, kext, scores, 2048, 2048, 576, 576, 576, 2048,
      1179648L, 1179648L, 1, 1000000, 16, 1000000, 1, 4194304L, 1, 0L,
      0.07216878364870322f);
  // GVW: vwT[z][d][s] = sum_c W_v[h][d][c] * kv[b][s][c]   (z=b*16+h)
  //   A = wkv_b V-part (idxA=h, stride 131072), B = kext (idxB=b), single launch
  //   (runs after G5: vwT region overlays dead qext; before softmax: kext alive)
  gemm_kernel<false,false,false><<<dim3(16,1,32),256,0,stream>>>(
      wkvb_bf + 65536, kext, vwT, 128, 2048, 512, 512, KEXT, 2048,
      131072L, 1179648L, 1, 16, 16, 2, 1, 262144L, 1, 0L, 1.0f);
  // softmax: fp32 probs to d_out (full rows incl. zeros), packed bf16 probs to ws
  softmax_rows<<<dim3(65536),dim3(256),0,stream>>>(scores, probs);
  // GPV: out_h = probs @ vwT[z]^T  (per z: 2048 x 128, triangular-K), single launch
  //   C layout outcat[b][s][h*128+d]: cOff = (z/16)*4194304 + (z%16)*128
  gemm_kernel<false,true,false><<<dim3(1,16,32),256,0,stream>>>(
      probs, vwT, outcat, 2048, 128, 2048, 0, 2048, 2048,
      (long)TRI_Z, 262144L, 1, 1000000, 1, 1000000, 16, 4194304L, 16, 128L, 1.0f);
  // G8: attn_out = outcat @ wo^T  (4096 x 2048, K=2048) fp32 out
  gemm_kernel<true,false,false><<<dim3(16,32,1),256,0,stream>>>(
      outcat, wo_bf, attn_out, 4096, 2048, 2048, 2048, 2048, 2048,
      0L, 0L, 1, 1, 1, 1, 1, 0L, 1, 0L, 1.0f);
}